// Round 2
// baseline (84.976 us; speedup 1.0000x reference)
//
#include <hip/hip_runtime.h>
#include <hip/hip_bf16.h>

// Problem: B=32, D=2048, NB=16, BS=512 (fp32 I/O per reference)
//   out[b,r] = g[b, r>>7] * dot(W[r,:], x[b,:]) + bias[r]
//   g = sigmoid(x @ gate_w + gate_b); zero the 8 smallest gates per sample.
// Block id of flat (r,c) is r//128 since c<2048 never crosses the 262144 boundary.

#define D_DIM 2048
#define B_DIM 32
#define NB_DIM 16
#define KSPLIT 8                   // 32 row-groups x 8 k-slices = 256 blocks
#define KCHUNK (D_DIM / KSPLIT)    // 256

typedef __attribute__((ext_vector_type(4))) float f32x4;
typedef __attribute__((ext_vector_type(8))) float f32x8;
typedef __attribute__((ext_vector_type(8))) __bf16 bf16x8;

static __device__ __forceinline__ __bf16 f2bf(float f) {
    unsigned u = __builtin_bit_cast(unsigned, f);
    u += 0x7fffu + ((u >> 16) & 1u);           // round-to-nearest-even
    unsigned short h = (unsigned short)(u >> 16);
    return __builtin_bit_cast(__bf16, h);
}

static __device__ __forceinline__ bf16x8 load_cvt8(const float* p) {
    const f32x8 v = *(const f32x8*)p;          // 32B: two dwordx4
    bf16x8 r;
#pragma unroll
    for (int i = 0; i < 8; ++i) r[i] = f2bf(v[i]);
    return r;
}

// ---------------- Kernel 1: gates (fp32 throughout) ----------------
__global__ __launch_bounds__(256) void gates_kernel(
    const float* __restrict__ X,   // [32][2048]
    const float* __restrict__ GW,  // [2048][16]
    const float* __restrict__ GB,  // [16]
    float* __restrict__ gates)     // [32][16]
{
    __shared__ float red[NB_DIM][256];
    __shared__ float sg[NB_DIM];
    const int b = blockIdx.x;
    const int t = threadIdx.x;

    float acc[NB_DIM];
#pragma unroll
    for (int n = 0; n < NB_DIM; ++n) acc[n] = 0.f;

#pragma unroll
    for (int i = 0; i < D_DIM / 256; ++i) {
        const int c = t + i * 256;
        const float xv = X[b * D_DIM + c];
        const float* gw = GW + c * NB_DIM;
#pragma unroll
        for (int n = 0; n < NB_DIM; ++n) acc[n] += xv * gw[n];
    }
#pragma unroll
    for (int n = 0; n < NB_DIM; ++n) red[n][t] = acc[n];
    __syncthreads();
    for (int s = 128; s > 0; s >>= 1) {
        if (t < s) {
#pragma unroll
            for (int n = 0; n < NB_DIM; ++n) red[n][t] += red[n][t + s];
        }
        __syncthreads();
    }
    if (t < NB_DIM) {
        const float v = red[t][0] + GB[t];
        sg[t] = 1.f / (1.f + __expf(-v));
    }
    __syncthreads();
    if (t < NB_DIM) {
        const float g = sg[t];
        int rank = 0;  // gates smaller than g (ties: lower index counts smaller, matching lax.top_k)
#pragma unroll
        for (int m = 0; m < NB_DIM; ++m) {
            const float gm = sg[m];
            if (gm < g || (gm == g && m < t)) rank++;
        }
        gates[b * NB_DIM + t] = (rank >= NB_DIM / 2) ? g : 0.f;
    }
}

// ---------------- Kernel 2: split-K GEMM partials (bf16 MFMA, fp32 in) ----------------
// part[ks][b][r] = sum_{c in slice ks} W[r][c] * x[b][c]
// Grid 256 = 32 row-groups (64 rows) x 8 k-slices; 4 waves/block, wave owns 16 rows x all 32 b.
// A-frag (16x16x32): lane holds A[m=lane&15][k=(lane>>4)*8 + 0..7]; B-frag symmetric.
__global__ __launch_bounds__(256) void main_gemm(
    const float* __restrict__ W,   // [2048][2048]
    const float* __restrict__ X,   // [32][2048]
    float* __restrict__ part)      // [KSPLIT][32][2048]
{
    const int bid  = blockIdx.x;
    const int ks   = bid & (KSPLIT - 1);
    const int rg   = bid >> 3;
    const int wave = threadIdx.x >> 6;
    const int lane = threadIdx.x & 63;
    const int l15  = lane & 15;
    const int q    = lane >> 4;

    const int r0 = rg * 64 + wave * 16;
    const int k0 = ks * KCHUNK;

    const float* arow = W + (size_t)(r0 + l15) * D_DIM + k0 + q * 8;
    const float* b0p  = X + (size_t)(l15)      * D_DIM + k0 + q * 8;
    const float* b1p  = X + (size_t)(l15 + 16) * D_DIM + k0 + q * 8;

    f32x4 acc0 = {0.f, 0.f, 0.f, 0.f};
    f32x4 acc1 = {0.f, 0.f, 0.f, 0.f};

#pragma unroll
    for (int kk = 0; kk < KCHUNK / 32; ++kk) {   // 8 MFMA k-steps
        const bf16x8 av  = load_cvt8(arow + kk * 32);
        const bf16x8 bv0 = load_cvt8(b0p  + kk * 32);
        const bf16x8 bv1 = load_cvt8(b1p  + kk * 32);
        acc0 = __builtin_amdgcn_mfma_f32_16x16x32_bf16(av, bv0, acc0, 0, 0, 0);
        acc1 = __builtin_amdgcn_mfma_f32_16x16x32_bf16(av, bv1, acc1, 0, 0, 0);
    }

    // C/D layout: col(n=batch) = lane&15, row(m=W-row) = (lane>>4)*4 + reg
    float* p0 = part + (size_t)ks * (B_DIM * D_DIM) + (size_t)l15 * D_DIM        + r0 + q * 4;
    float* p1 = part + (size_t)ks * (B_DIM * D_DIM) + (size_t)(l15 + 16) * D_DIM + r0 + q * 4;
    *(f32x4*)p0 = acc0;
    *(f32x4*)p1 = acc1;
}

// ---------------- Kernel 3: reduce + gate + bias -> fp32 out ----------------
__global__ __launch_bounds__(256) void reduce_kernel(
    const float* __restrict__ part,   // [KSPLIT][32][2048]
    const float* __restrict__ gates,  // [32][16]
    const float* __restrict__ bias,   // [2048]
    float* __restrict__ out)          // [32][2048]
{
    const int t   = blockIdx.x * 256 + threadIdx.x;   // 16384 threads
    const int idx = t * 4;
    const int b   = idx >> 11;
    const int r   = idx & (D_DIM - 1);

    f32x4 s = {0.f, 0.f, 0.f, 0.f};
#pragma unroll
    for (int ks = 0; ks < KSPLIT; ++ks) {
        s += *(const f32x4*)(part + (size_t)ks * (B_DIM * D_DIM) + idx);
    }
    const float g = gates[b * NB_DIM + (r >> 7)];
    const f32x4 bi = *(const f32x4*)(bias + r);

    f32x4 y;
#pragma unroll
    for (int i = 0; i < 4; ++i) y[i] = g * s[i] + bi[i];
    *(f32x4*)(out + idx) = y;
}

extern "C" void kernel_launch(void* const* d_in, const int* in_sizes, int n_in,
                              void* d_out, int out_size, void* d_ws, size_t ws_size,
                              hipStream_t stream) {
    const float* x    = (const float*)d_in[0];  // [32][2048]
    const float* gw   = (const float*)d_in[1];  // [2048][16]
    const float* gb   = (const float*)d_in[2];  // [16]
    const float* w    = (const float*)d_in[3];  // [2048][2048]
    const float* bias = (const float*)d_in[4];  // [2048]
    float* out = (float*)d_out;

    float* part  = (float*)d_ws;  // 8*32*2048 fp32 = 2 MB
    float* gates = (float*)((char*)d_ws + (size_t)KSPLIT * B_DIM * D_DIM * sizeof(float));

    gates_kernel<<<B_DIM, 256, 0, stream>>>(x, gw, gb, gates);
    main_gemm<<<32 * KSPLIT, 256, 0, stream>>>(w, x, part);
    reduce_kernel<<<(B_DIM * D_DIM) / (256 * 4), 256, 0, stream>>>(part, gates, bias, out);
}